// Round 1
// baseline (654.209 us; speedup 1.0000x reference)
//
#include <hip/hip_runtime.h>

// ---------------------------------------------------------------------------
// Transformer block fwd on MI355X (gfx950), bf16 MFMA pipeline.
// B=8 T=1024 C=1024 H=16 D=64, M = B*T = 8192.
// ---------------------------------------------------------------------------

typedef __bf16 bf16;
typedef bf16 bf16x8 __attribute__((ext_vector_type(8)));
typedef bf16 bf16x4 __attribute__((ext_vector_type(4)));
typedef float f32x4 __attribute__((ext_vector_type(4)));

#define GLOAD_LDS16(g, l)                                                      \
  __builtin_amdgcn_global_load_lds(                                            \
      (const __attribute__((address_space(1))) void*)(g),                      \
      (__attribute__((address_space(3))) void*)(l), 16, 0, 0)

static __device__ __forceinline__ f32x4 mfma16(bf16x8 a, bf16x8 b, f32x4 c) {
  return __builtin_amdgcn_mfma_f32_16x16x32_bf16(a, b, c, 0, 0, 0);
}

// ---------------- LayerNorm: fp32 [8192,1024] -> bf16 [8192,1024] ----------
__global__ __launch_bounds__(256) void ln_kernel(const float* __restrict__ x,
                                                 const float* __restrict__ w,
                                                 const float* __restrict__ b,
                                                 bf16* __restrict__ out) {
  const int row = blockIdx.x;
  const int t = threadIdx.x;
  const float4 v = reinterpret_cast<const float4*>(x + (size_t)row * 1024)[t];
  float s = v.x + v.y + v.z + v.w;
  float s2 = v.x * v.x + v.y * v.y + v.z * v.z + v.w * v.w;
#pragma unroll
  for (int off = 32; off >= 1; off >>= 1) {
    s += __shfl_xor(s, off, 64);
    s2 += __shfl_xor(s2, off, 64);
  }
  __shared__ float red[8];
  if ((t & 63) == 0) {
    red[t >> 6] = s;
    red[4 + (t >> 6)] = s2;
  }
  __syncthreads();
  s = red[0] + red[1] + red[2] + red[3];
  s2 = red[4] + red[5] + red[6] + red[7];
  const float mean = s * (1.0f / 1024.0f);
  const float var = s2 * (1.0f / 1024.0f) - mean * mean;
  const float rstd = rsqrtf(var + 1e-5f);
  const float4 wv = reinterpret_cast<const float4*>(w)[t];
  const float4 bv = reinterpret_cast<const float4*>(b)[t];
  bf16x4 o;
  o[0] = (bf16)((v.x - mean) * rstd * wv.x + bv.x);
  o[1] = (bf16)((v.y - mean) * rstd * wv.y + bv.y);
  o[2] = (bf16)((v.z - mean) * rstd * wv.z + bv.z);
  o[3] = (bf16)((v.w - mean) * rstd * wv.w + bv.w);
  *reinterpret_cast<bf16x4*>(out + (size_t)row * 1024 + t * 4) = o;
}

// ---------------- Weight transpose + cast: W fp32 [K,N] -> Wt bf16 [N,K] ----
__global__ __launch_bounds__(256) void transpose_cast_kernel(
    const float* __restrict__ W, bf16* __restrict__ Wt, int K, int N) {
  __shared__ float tile[64][65];
  const int c0 = blockIdx.x * 64;  // N dim
  const int r0 = blockIdx.y * 64;  // K dim
  const int t = threadIdx.x;
  const int tr = t >> 4;           // 0..15
  const int tc = (t & 15) * 4;     // 0..60
#pragma unroll
  for (int rr = 0; rr < 4; ++rr) {
    const int lr = rr * 16 + tr;
    const float4 v =
        *reinterpret_cast<const float4*>(&W[(size_t)(r0 + lr) * N + c0 + tc]);
    tile[lr][tc] = v.x;
    tile[lr][tc + 1] = v.y;
    tile[lr][tc + 2] = v.z;
    tile[lr][tc + 3] = v.w;
  }
  __syncthreads();
#pragma unroll
  for (int rr = 0; rr < 4; ++rr) {
    const int ln = rr * 16 + tr;
    bf16x4 o;
#pragma unroll
    for (int i = 0; i < 4; ++i) o[i] = (bf16)tile[tc + i][ln];
    *reinterpret_cast<bf16x4*>(&Wt[(size_t)(c0 + ln) * K + r0 + tc]) = o;
  }
}

// ---------------- GEMM: C[M,N] = A[M,K] * Bt[N,K]^T (+epilogue) -------------
// 128x128 tile, BK=64, 256 threads (4 waves, 2x2), 4x4 16x16x32 frags/wave.
// LDS XOR-swizzle (byte ^= (row&7)<<4) applied via pre-swizzled global source
// for global_load_lds staging + swizzled ds_read (rule #21: both sides).
// EPI: 0 = bias -> bf16 out; 1 = bias+gelu -> bf16 out; 2 = bias+resid -> f32.
template <int EPI>
__global__ __launch_bounds__(256) void gemm_kernel(
    const bf16* __restrict__ A, const bf16* __restrict__ Bt,
    const float* __restrict__ bias, const float* resid, float* outf,
    bf16* __restrict__ outb, int Ndim, int Kdim) {
  __shared__ __align__(16) bf16 As[128 * 64];
  __shared__ __align__(16) bf16 Bs[128 * 64];
  const int t = threadIdx.x;
  const int l = t & 63;
  const int w = t >> 6;
  const int lg = l >> 4, lc = l & 15;
  const int wr = w >> 1, wc = w & 1;
  const int m0 = blockIdx.y * 128;
  const int n0 = blockIdx.x * 128;

  f32x4 acc[4][4];
#pragma unroll
  for (int m = 0; m < 4; ++m)
#pragma unroll
    for (int n = 0; n < 4; ++n) acc[m][n] = {0.f, 0.f, 0.f, 0.f};

  const int sr = t >> 3;        // staging row sub-index 0..31
  const int sc = (t & 7) * 8;   // staging chunk (elems)

  for (int k0 = 0; k0 < Kdim; k0 += 64) {
    __syncthreads();
#pragma unroll
    for (int j = 0; j < 4; ++j) {
      const int row = j * 32 + sr;
      const int col = sc ^ ((row & 7) * 8);  // inverse swizzle on source
      GLOAD_LDS16(A + (size_t)(m0 + row) * Kdim + k0 + col,
                  &As[j * 2048 + t * 8]);
    }
#pragma unroll
    for (int j = 0; j < 4; ++j) {
      const int row = j * 32 + sr;
      const int col = sc ^ ((row & 7) * 8);
      GLOAD_LDS16(Bt + (size_t)(n0 + row) * Kdim + k0 + col,
                  &Bs[j * 2048 + t * 8]);
    }
    __syncthreads();
#pragma unroll
    for (int ks = 0; ks < 2; ++ks) {
      bf16x8 af[4], bfr[4];
#pragma unroll
      for (int m = 0; m < 4; ++m) {
        const int row = wr * 64 + m * 16 + lc;
        af[m] = *reinterpret_cast<const bf16x8*>(
            &As[row * 64 + ((ks * 32 + 8 * lg) ^ ((row & 7) * 8))]);
      }
#pragma unroll
      for (int n = 0; n < 4; ++n) {
        const int row = wc * 64 + n * 16 + lc;
        bfr[n] = *reinterpret_cast<const bf16x8*>(
            &Bs[row * 64 + ((ks * 32 + 8 * lg) ^ ((row & 7) * 8))]);
      }
#pragma unroll
      for (int m = 0; m < 4; ++m)
#pragma unroll
        for (int n = 0; n < 4; ++n) acc[m][n] = mfma16(af[m], bfr[n], acc[m][n]);
    }
  }

#pragma unroll
  for (int n = 0; n < 4; ++n) {
    const int col = n0 + wc * 64 + n * 16 + lc;
    const float bv = bias[col];
#pragma unroll
    for (int m = 0; m < 4; ++m) {
      const int row0 = m0 + wr * 64 + m * 16 + lg * 4;
#pragma unroll
      for (int r = 0; r < 4; ++r) {
        const size_t idx = (size_t)(row0 + r) * Ndim + col;
        const float v = acc[m][n][r] + bv;
        if (EPI == 0) {
          outb[idx] = (bf16)v;
        } else if (EPI == 1) {
          const float g =
              0.5f * v *
              (1.0f + tanhf(0.79788456080286535588f * (v + 0.044715f * v * v * v)));
          outb[idx] = (bf16)g;
        } else {
          outf[idx] = v + resid[idx];
        }
      }
    }
  }
}

// ---------------- Flash attention (causal), Q-tile 128, KV-tile 64 ----------
// qkv bf16 [B,T,3C]; per (b,h): Q rows at +h*64, K at +1024+h*64, V at +2048.
// Scale is 1/sqrt(C) = 1/32 (faithful to reference).
__global__ __launch_bounds__(256) void attn_kernel(const bf16* __restrict__ qkv,
                                                   bf16* __restrict__ y) {
  const int qb0 = blockIdx.x * 128;
  const int h = blockIdx.y;
  const int b = blockIdx.z;
  const int t = threadIdx.x;
  const int l = t & 63;
  const int w = t >> 6;
  const int lg = l >> 4, lc = l & 15;

  __shared__ __align__(16) bf16 Qs[128 * 64];
  __shared__ __align__(16) bf16 Ks[64 * 64];
  __shared__ __align__(16) bf16 Vt[64 * 72];   // [d][kv], pad 72
  __shared__ __align__(16) bf16 Ps[4][32 * 64];  // per-wave P

  const size_t base = (size_t)b * 1024 * 3072;
  const int sr = t >> 3;
  const int sc = (t & 7) * 8;

  // stage Q (swizzled rows of 128B)
#pragma unroll
  for (int j = 0; j < 4; ++j) {
    const int row = j * 32 + sr;
    const int col = sc ^ ((row & 7) * 8);
    GLOAD_LDS16(qkv + base + (size_t)(qb0 + row) * 3072 + h * 64 + col,
                &Qs[j * 2048 + t * 8]);
  }
  __syncthreads();

  bf16x8 qf[2][2];
#pragma unroll
  for (int mf = 0; mf < 2; ++mf)
#pragma unroll
    for (int ks = 0; ks < 2; ++ks) {
      const int row = w * 32 + mf * 16 + lc;
      qf[mf][ks] = *reinterpret_cast<const bf16x8*>(
          &Qs[row * 64 + ((ks * 32 + 8 * lg) ^ ((row & 7) * 8))]);
    }

  float mrow[2][4], lrow[2][4];
  f32x4 oacc[2][4];
#pragma unroll
  for (int mf = 0; mf < 2; ++mf)
#pragma unroll
    for (int r = 0; r < 4; ++r) {
      mrow[mf][r] = -1e30f;
      lrow[mf][r] = 0.f;
    }
#pragma unroll
  for (int mf = 0; mf < 2; ++mf)
#pragma unroll
    for (int nd = 0; nd < 4; ++nd) oacc[mf][nd] = {0.f, 0.f, 0.f, 0.f};

  const int nkv = (qb0 >> 6) + 2;  // causal: only tiles with kv0 < qb0+128
  for (int kt = 0; kt < nkv; ++kt) {
    const int kv0 = kt * 64;
    __syncthreads();  // prev iteration's reads of Ks/Vt done
#pragma unroll
    for (int j = 0; j < 2; ++j) {
      const int row = j * 32 + sr;
      const int col = sc ^ ((row & 7) * 8);
      GLOAD_LDS16(
          qkv + base + (size_t)(kv0 + row) * 3072 + 1024 + h * 64 + col,
          &Ks[j * 2048 + t * 8]);
    }
#pragma unroll
    for (int j = 0; j < 2; ++j) {
      const int kv = j * 32 + sr;
      const bf16x8 vv = *reinterpret_cast<const bf16x8*>(
          qkv + base + (size_t)(kv0 + kv) * 3072 + 2048 + h * 64 + sc);
#pragma unroll
      for (int i = 0; i < 8; ++i) Vt[(sc + i) * 72 + kv] = vv[i];
    }
    __syncthreads();

    // S = Q K^T (per wave: 32 q-rows x 64 kv-cols)
    f32x4 s[2][4];
#pragma unroll
    for (int mf = 0; mf < 2; ++mf)
#pragma unroll
      for (int nf = 0; nf < 4; ++nf) s[mf][nf] = {0.f, 0.f, 0.f, 0.f};
#pragma unroll
    for (int ks = 0; ks < 2; ++ks) {
      bf16x8 kf[4];
#pragma unroll
      for (int nf = 0; nf < 4; ++nf) {
        const int row = nf * 16 + lc;
        kf[nf] = *reinterpret_cast<const bf16x8*>(
            &Ks[row * 64 + ((ks * 32 + 8 * lg) ^ ((row & 7) * 8))]);
      }
#pragma unroll
      for (int mf = 0; mf < 2; ++mf)
#pragma unroll
        for (int nf = 0; nf < 4; ++nf)
          s[mf][nf] = mfma16(qf[mf][ks], kf[nf], s[mf][nf]);
    }

    // scale + causal mask
#pragma unroll
    for (int mf = 0; mf < 2; ++mf)
#pragma unroll
      for (int nf = 0; nf < 4; ++nf)
#pragma unroll
        for (int r = 0; r < 4; ++r) {
          const int qg = qb0 + w * 32 + mf * 16 + lg * 4 + r;
          const int kg = kv0 + nf * 16 + lc;
          const float sv = s[mf][nf][r] * 0.03125f;
          s[mf][nf][r] = (kg <= qg) ? sv : -1e30f;
        }

    // online softmax (row = lane-local: mf*16 + lg*4 + r; 16 lanes/row)
    float alpha[2][4];
#pragma unroll
    for (int mf = 0; mf < 2; ++mf)
#pragma unroll
      for (int r = 0; r < 4; ++r) {
        float pm = fmaxf(fmaxf(s[mf][0][r], s[mf][1][r]),
                         fmaxf(s[mf][2][r], s[mf][3][r]));
#pragma unroll
        for (int off = 8; off >= 1; off >>= 1)
          pm = fmaxf(pm, __shfl_xor(pm, off, 64));
        const float mnew = fmaxf(mrow[mf][r], pm);
        alpha[mf][r] = __expf(mrow[mf][r] - mnew);
        mrow[mf][r] = mnew;
      }
#pragma unroll
    for (int mf = 0; mf < 2; ++mf)
#pragma unroll
      for (int r = 0; r < 4; ++r) {
        float rs = 0.f;
#pragma unroll
        for (int nf = 0; nf < 4; ++nf) {
          const float p = __expf(s[mf][nf][r] - mrow[mf][r]);
          s[mf][nf][r] = p;
          rs += p;
        }
#pragma unroll
        for (int off = 8; off >= 1; off >>= 1) rs += __shfl_xor(rs, off, 64);
        lrow[mf][r] = lrow[mf][r] * alpha[mf][r] + rs;
#pragma unroll
        for (int nd = 0; nd < 4; ++nd) oacc[mf][nd][r] *= alpha[mf][r];
      }

    // P -> bf16 -> per-wave LDS (swizzled); same-wave DS ordering, no barrier
#pragma unroll
    for (int mf = 0; mf < 2; ++mf)
#pragma unroll
      for (int nf = 0; nf < 4; ++nf)
#pragma unroll
        for (int r = 0; r < 4; ++r) {
          const int pr = mf * 16 + lg * 4 + r;
          const int pc = nf * 16 + lc;
          Ps[w][pr * 64 + (pc ^ ((pr & 7) * 8))] = (bf16)s[mf][nf][r];
        }

    // O += P @ V
#pragma unroll
    for (int ks = 0; ks < 2; ++ks) {
      bf16x8 pf[2], vf[4];
#pragma unroll
      for (int mf = 0; mf < 2; ++mf) {
        const int row = mf * 16 + lc;
        pf[mf] = *reinterpret_cast<const bf16x8*>(
            &Ps[w][row * 64 + ((ks * 32 + 8 * lg) ^ ((row & 7) * 8))]);
      }
#pragma unroll
      for (int nd = 0; nd < 4; ++nd)
        vf[nd] = *reinterpret_cast<const bf16x8*>(
            &Vt[(nd * 16 + lc) * 72 + ks * 32 + 8 * lg]);
#pragma unroll
      for (int mf = 0; mf < 2; ++mf)
#pragma unroll
        for (int nd = 0; nd < 4; ++nd)
          oacc[mf][nd] = mfma16(pf[mf], vf[nd], oacc[mf][nd]);
    }
  }

  // epilogue: y[b, q, h*64+d] = O / l
  const size_t ybase = (size_t)b * 1024 * 1024;
#pragma unroll
  for (int mf = 0; mf < 2; ++mf)
#pragma unroll
    for (int nd = 0; nd < 4; ++nd)
#pragma unroll
      for (int r = 0; r < 4; ++r) {
        const int qg = qb0 + w * 32 + mf * 16 + lg * 4 + r;
        const int d = nd * 16 + lc;
        y[ybase + (size_t)qg * 1024 + h * 64 + d] =
            (bf16)(oacc[mf][nd][r] / lrow[mf][r]);
      }
}

// ---------------------------------------------------------------------------
// Workspace layout (bytes). Total 109,051,904 (~104 MiB).
//   WqkvT 0..6291456 | WoT ..8388608 | WfcT ..16777216 | WpT ..25165824
//   h1/h2 ..41943040 | qkv ..92274688 | y ..109051904 | fc aliases qkv+y
//   x1 lives in d_out (fp32 [8192,1024]).
// ---------------------------------------------------------------------------
extern "C" void kernel_launch(void* const* d_in, const int* in_sizes, int n_in,
                              void* d_out, int out_size, void* d_ws,
                              size_t ws_size, hipStream_t stream) {
  (void)in_sizes; (void)n_in; (void)out_size; (void)ws_size;
  const float* x    = (const float*)d_in[0];
  const float* Wqkv = (const float*)d_in[1];
  const float* bqkv = (const float*)d_in[2];
  const float* Wo   = (const float*)d_in[3];
  const float* bo   = (const float*)d_in[4];
  const float* ln1w = (const float*)d_in[5];
  const float* ln1b = (const float*)d_in[6];
  const float* ln2w = (const float*)d_in[7];
  const float* ln2b = (const float*)d_in[8];
  const float* Wfc  = (const float*)d_in[9];
  const float* bfc  = (const float*)d_in[10];
  const float* Wp   = (const float*)d_in[11];
  const float* bp   = (const float*)d_in[12];
  float* out = (float*)d_out;
  char* ws = (char*)d_ws;

  bf16* WqkvT = (bf16*)(ws + 0);
  bf16* WoT   = (bf16*)(ws + 6291456);
  bf16* WfcT  = (bf16*)(ws + 8388608);
  bf16* WpT   = (bf16*)(ws + 16777216);
  bf16* h1    = (bf16*)(ws + 25165824);  // also h2
  bf16* qkv   = (bf16*)(ws + 41943040);
  bf16* yb    = (bf16*)(ws + 92274688);
  bf16* fc    = (bf16*)(ws + 41943040);  // aliases qkv+y (both dead by then)
  float* x1   = out;                      // residual buffer in d_out

  // weights: cast + transpose to [N,K] bf16
  transpose_cast_kernel<<<dim3(48, 16), 256, 0, stream>>>(Wqkv, WqkvT, 1024, 3072);
  transpose_cast_kernel<<<dim3(16, 16), 256, 0, stream>>>(Wo, WoT, 1024, 1024);
  transpose_cast_kernel<<<dim3(64, 16), 256, 0, stream>>>(Wfc, WfcT, 1024, 4096);
  transpose_cast_kernel<<<dim3(16, 64), 256, 0, stream>>>(Wp, WpT, 4096, 1024);

  // h = LN1(x)
  ln_kernel<<<8192, 256, 0, stream>>>(x, ln1w, ln1b, h1);
  // qkv = h @ Wqkv + bqkv
  gemm_kernel<0><<<dim3(24, 64), 256, 0, stream>>>(h1, WqkvT, bqkv, nullptr,
                                                   nullptr, qkv, 3072, 1024);
  // y = attention(qkv)
  attn_kernel<<<dim3(8, 16, 8), 256, 0, stream>>>(qkv, yb);
  // x1 = x + y @ Wo + bo
  gemm_kernel<2><<<dim3(8, 64), 256, 0, stream>>>(yb, WoT, bo, x, x1, nullptr,
                                                  1024, 1024);
  // h2 = LN2(x1)
  ln_kernel<<<8192, 256, 0, stream>>>(x1, ln2w, ln2b, h1);
  // fc = gelu(h2 @ Wfc + bfc)
  gemm_kernel<1><<<dim3(32, 64), 256, 0, stream>>>(h1, WfcT, bfc, nullptr,
                                                   nullptr, fc, 4096, 1024);
  // out = x1 + fc @ Wp + bp
  gemm_kernel<2><<<dim3(8, 64), 256, 0, stream>>>(fc, WpT, bp, x1, out, nullptr,
                                                  1024, 4096);
}

// Round 2
// 525.758 us; speedup vs baseline: 1.2443x; 1.2443x over previous
//
#include <hip/hip_runtime.h>

// ---------------------------------------------------------------------------
// Transformer block fwd on MI355X (gfx950), bf16 MFMA pipeline.
// B=8 T=1024 C=1024 H=16 D=64, M = B*T = 8192.
// R2: attention rewritten (dbuf K/V, 1 barrier/tile, defer-max softmax,
//     P aliases Q-LDS, vectorized V transpose), XCD swizzle on attn+GEMM.
// ---------------------------------------------------------------------------

typedef __bf16 bf16;
typedef bf16 bf16x8 __attribute__((ext_vector_type(8)));
typedef bf16 bf16x4 __attribute__((ext_vector_type(4)));
typedef float f32x4 __attribute__((ext_vector_type(4)));

#define GLOAD_LDS16(g, l)                                                      \
  __builtin_amdgcn_global_load_lds(                                            \
      (const __attribute__((address_space(1))) void*)(g),                      \
      (__attribute__((address_space(3))) void*)(l), 16, 0, 0)

#if __has_builtin(__builtin_amdgcn_exp2f)
#define EXP2F(x) __builtin_amdgcn_exp2f(x)
#else
#define EXP2F(x) exp2f(x)
#endif

static __device__ __forceinline__ f32x4 mfma16(bf16x8 a, bf16x8 b, f32x4 c) {
  return __builtin_amdgcn_mfma_f32_16x16x32_bf16(a, b, c, 0, 0, 0);
}

// ---------------- LayerNorm: fp32 [8192,1024] -> bf16 [8192,1024] ----------
__global__ __launch_bounds__(256) void ln_kernel(const float* __restrict__ x,
                                                 const float* __restrict__ w,
                                                 const float* __restrict__ b,
                                                 bf16* __restrict__ out) {
  const int row = blockIdx.x;
  const int t = threadIdx.x;
  const float4 v = reinterpret_cast<const float4*>(x + (size_t)row * 1024)[t];
  float s = v.x + v.y + v.z + v.w;
  float s2 = v.x * v.x + v.y * v.y + v.z * v.z + v.w * v.w;
#pragma unroll
  for (int off = 32; off >= 1; off >>= 1) {
    s += __shfl_xor(s, off, 64);
    s2 += __shfl_xor(s2, off, 64);
  }
  __shared__ float red[8];
  if ((t & 63) == 0) {
    red[t >> 6] = s;
    red[4 + (t >> 6)] = s2;
  }
  __syncthreads();
  s = red[0] + red[1] + red[2] + red[3];
  s2 = red[4] + red[5] + red[6] + red[7];
  const float mean = s * (1.0f / 1024.0f);
  const float var = s2 * (1.0f / 1024.0f) - mean * mean;
  const float rstd = rsqrtf(var + 1e-5f);
  const float4 wv = reinterpret_cast<const float4*>(w)[t];
  const float4 bv = reinterpret_cast<const float4*>(b)[t];
  bf16x4 o;
  o[0] = (bf16)((v.x - mean) * rstd * wv.x + bv.x);
  o[1] = (bf16)((v.y - mean) * rstd * wv.y + bv.y);
  o[2] = (bf16)((v.z - mean) * rstd * wv.z + bv.z);
  o[3] = (bf16)((v.w - mean) * rstd * wv.w + bv.w);
  *reinterpret_cast<bf16x4*>(out + (size_t)row * 1024 + t * 4) = o;
}

// ---------------- Weight transpose + cast: W fp32 [K,N] -> Wt bf16 [N,K] ----
__global__ __launch_bounds__(256) void transpose_cast_kernel(
    const float* __restrict__ W, bf16* __restrict__ Wt, int K, int N) {
  __shared__ float tile[64][65];
  const int c0 = blockIdx.x * 64;  // N dim
  const int r0 = blockIdx.y * 64;  // K dim
  const int t = threadIdx.x;
  const int tr = t >> 4;           // 0..15
  const int tc = (t & 15) * 4;     // 0..60
#pragma unroll
  for (int rr = 0; rr < 4; ++rr) {
    const int lr = rr * 16 + tr;
    const float4 v =
        *reinterpret_cast<const float4*>(&W[(size_t)(r0 + lr) * N + c0 + tc]);
    tile[lr][tc] = v.x;
    tile[lr][tc + 1] = v.y;
    tile[lr][tc + 2] = v.z;
    tile[lr][tc + 3] = v.w;
  }
  __syncthreads();
#pragma unroll
  for (int rr = 0; rr < 4; ++rr) {
    const int ln = rr * 16 + tr;
    bf16x4 o;
#pragma unroll
    for (int i = 0; i < 4; ++i) o[i] = (bf16)tile[tc + i][ln];
    *reinterpret_cast<bf16x4*>(&Wt[(size_t)(c0 + ln) * K + r0 + tc]) = o;
  }
}

// ---------------- GEMM: C[M,N] = A[M,K] * Bt[N,K]^T (+epilogue) -------------
// 128x128 tile, BK=64, 256 threads (4 waves, 2x2), 4x4 16x16x32 frags/wave.
// XCD-aware block swizzle (all grids here are multiples of 8 blocks).
// EPI: 0 = bias -> bf16 out; 1 = bias+gelu -> bf16 out; 2 = bias+resid -> f32.
template <int EPI>
__global__ __launch_bounds__(256) void gemm_kernel(
    const bf16* __restrict__ A, const bf16* __restrict__ Bt,
    const float* __restrict__ bias, const float* resid, float* outf,
    bf16* __restrict__ outb, int Ndim, int Kdim) {
  __shared__ __align__(16) bf16 As[128 * 64];
  __shared__ __align__(16) bf16 Bs[128 * 64];
  const int t = threadIdx.x;
  const int l = t & 63;
  const int w = t >> 6;
  const int lg = l >> 4, lc = l & 15;
  const int wr = w >> 1, wc = w & 1;

  // XCD swizzle: contiguous chunk of tiles per XCD
  const int gx = gridDim.x;
  const int nwg = gx * gridDim.y;
  int flat = blockIdx.x + blockIdx.y * gx;
  if ((nwg & 7) == 0) {
    const int ch = nwg >> 3;
    flat = (flat & 7) * ch + (flat >> 3);
  }
  const int m0 = (flat / gx) * 128;
  const int n0 = (flat % gx) * 128;

  f32x4 acc[4][4];
#pragma unroll
  for (int m = 0; m < 4; ++m)
#pragma unroll
    for (int n = 0; n < 4; ++n) acc[m][n] = {0.f, 0.f, 0.f, 0.f};

  const int sr = t >> 3;        // staging row sub-index 0..31
  const int sc = (t & 7) * 8;   // staging chunk (elems)

  for (int k0 = 0; k0 < Kdim; k0 += 64) {
    __syncthreads();
#pragma unroll
    for (int j = 0; j < 4; ++j) {
      const int row = j * 32 + sr;
      const int col = sc ^ ((row & 7) * 8);  // inverse swizzle on source
      GLOAD_LDS16(A + (size_t)(m0 + row) * Kdim + k0 + col,
                  &As[j * 2048 + t * 8]);
    }
#pragma unroll
    for (int j = 0; j < 4; ++j) {
      const int row = j * 32 + sr;
      const int col = sc ^ ((row & 7) * 8);
      GLOAD_LDS16(Bt + (size_t)(n0 + row) * Kdim + k0 + col,
                  &Bs[j * 2048 + t * 8]);
    }
    __syncthreads();
#pragma unroll
    for (int ks = 0; ks < 2; ++ks) {
      bf16x8 af[4], bfr[4];
#pragma unroll
      for (int m = 0; m < 4; ++m) {
        const int row = wr * 64 + m * 16 + lc;
        af[m] = *reinterpret_cast<const bf16x8*>(
            &As[row * 64 + ((ks * 32 + 8 * lg) ^ ((row & 7) * 8))]);
      }
#pragma unroll
      for (int n = 0; n < 4; ++n) {
        const int row = wc * 64 + n * 16 + lc;
        bfr[n] = *reinterpret_cast<const bf16x8*>(
            &Bs[row * 64 + ((ks * 32 + 8 * lg) ^ ((row & 7) * 8))]);
      }
#pragma unroll
      for (int m = 0; m < 4; ++m)
#pragma unroll
        for (int n = 0; n < 4; ++n) acc[m][n] = mfma16(af[m], bfr[n], acc[m][n]);
    }
  }

#pragma unroll
  for (int n = 0; n < 4; ++n) {
    const int col = n0 + wc * 64 + n * 16 + lc;
    const float bv = bias[col];
#pragma unroll
    for (int m = 0; m < 4; ++m) {
      const int row0 = m0 + wr * 64 + m * 16 + lg * 4;
#pragma unroll
      for (int r = 0; r < 4; ++r) {
        const size_t idx = (size_t)(row0 + r) * Ndim + col;
        const float v = acc[m][n][r] + bv;
        if (EPI == 0) {
          outb[idx] = (bf16)v;
        } else if (EPI == 1) {
          const float g =
              0.5f * v *
              (1.0f + tanhf(0.79788456080286535588f * (v + 0.044715f * v * v * v)));
          outb[idx] = (bf16)g;
        } else {
          outf[idx] = v + resid[idx];
        }
      }
    }
  }
}

// ---------------- Flash attention (causal), Q-tile 128, KV-tile 64 ----------
// Double-buffered K (global_load_lds) and V (reg-staged transpose), one
// barrier per KV tile. P buffer aliases the dead Q staging LDS (per-wave).
// Softmax: exp2 with folded 1/sqrt(C) scale, defer-max (THR), lane-local
// partial row sums (single reduce at epilogue), mask only diagonal tiles.
__global__ __launch_bounds__(256) void attn_kernel(const bf16* __restrict__ qkv,
                                                   bf16* __restrict__ y) {
  // XCD swizzle: each XCD gets one full batch's 128 (h,qt) work items.
  const int flat = blockIdx.x + (blockIdx.y << 3) + (blockIdx.z << 7);
  const int swz = (flat & 7) * 128 + (flat >> 3);
  const int qt = swz & 7;
  const int h = (swz >> 3) & 15;
  const int b = swz >> 7;
  const int qb0 = qt * 128;

  const int t = threadIdx.x;
  const int l = t & 63;
  const int w = t >> 6;
  const int lg = l >> 4, lc = l & 15;

  __shared__ __align__(16) bf16 QPs[128 * 64];     // Q staging, then per-wave P
  __shared__ __align__(16) bf16 Ksm[2][64 * 64];   // K dbuf (swizzled rows)
  __shared__ __align__(16) bf16 Vtm[2][64 * 64];   // V^T dbuf (swizzled rows)

  const size_t base = (size_t)b * 1024 * 3072;
  const int sr = t >> 3;
  const int sc = (t & 7) * 8;
  const int vd0 = (t & 31) * 2;   // V-transpose: this thread's 2 d-rows
  const int vk0 = (t >> 5) * 8;   // and 8 kv-cols

  // ---- prologue: stage Q + K0 (async LDS), issue V0 loads ----
#pragma unroll
  for (int j = 0; j < 4; ++j) {
    const int row = j * 32 + sr;
    const int col = sc ^ ((row & 7) * 8);
    GLOAD_LDS16(qkv + base + (size_t)(qb0 + row) * 3072 + h * 64 + col,
                &QPs[j * 2048 + t * 8]);
  }
#pragma unroll
  for (int j = 0; j < 2; ++j) {
    const int row = j * 32 + sr;
    const int col = sc ^ ((row & 7) * 8);
    GLOAD_LDS16(qkv + base + (size_t)row * 3072 + 1024 + h * 64 + col,
                &Ksm[0][j * 2048 + t * 8]);
  }
  unsigned int v8[8];
#pragma unroll
  for (int i = 0; i < 8; ++i)
    v8[i] = *reinterpret_cast<const unsigned int*>(
        qkv + base + (size_t)(vk0 + i) * 3072 + 2048 + h * 64 + vd0);
  __syncthreads();

  // Q fragments -> registers (QPs region becomes this wave's P buffer after)
  bf16x8 qf[2][2];
#pragma unroll
  for (int mf = 0; mf < 2; ++mf)
#pragma unroll
    for (int ks = 0; ks < 2; ++ks) {
      const int row = w * 32 + mf * 16 + lc;
      qf[mf][ks] = *reinterpret_cast<const bf16x8*>(
          &QPs[row * 64 + ((ks * 32 + 8 * lg) ^ ((row & 7) * 8))]);
    }
  // V0 -> Vtm[0] (register transpose, vectorized writes)
  {
    bf16x8 wlo, whi;
#pragma unroll
    for (int i = 0; i < 8; ++i) {
      wlo[i] = __builtin_bit_cast(bf16, (unsigned short)(v8[i] & 0xffffu));
      whi[i] = __builtin_bit_cast(bf16, (unsigned short)(v8[i] >> 16));
    }
    *reinterpret_cast<bf16x8*>(&Vtm[0][vd0 * 64 + (vk0 ^ ((vd0 & 7) * 8))]) = wlo;
    *reinterpret_cast<bf16x8*>(
        &Vtm[0][(vd0 + 1) * 64 + (vk0 ^ (((vd0 + 1) & 7) * 8))]) = whi;
  }
  __syncthreads();

  bf16* const Pw = &QPs[w * 2048];  // this wave's 32x64 P tile

  const float KS = 0.04508422f;  // (1/32) * log2(e)
  const float THR = 177.0f;      // defer-max threshold: exp bound 2^8

  float mrow[2][4], mK[2][4], lsum[2][4];
  f32x4 oacc[2][4];
#pragma unroll
  for (int mf = 0; mf < 2; ++mf)
#pragma unroll
    for (int r = 0; r < 4; ++r) {
      mrow[mf][r] = -1e30f;
      mK[mf][r] = 0.f;
      lsum[mf][r] = 0.f;
    }
#pragma unroll
  for (int mf = 0; mf < 2; ++mf)
#pragma unroll
    for (int nd = 0; nd < 4; ++nd) oacc[mf][nd] = {0.f, 0.f, 0.f, 0.f};

  const int nkv = qt * 2 + 2;
  for (int kt = 0; kt < nkv; ++kt) {
    const int cur = kt & 1, nxt = cur ^ 1;
    const int kv0t = kt << 6;
    const bool hasnext = (kt + 1 < nkv);

    // -- prefetch next tile: K -> LDS (async), V -> regs
    if (hasnext) {
      const int kn = (kt + 1) << 6;
#pragma unroll
      for (int j = 0; j < 2; ++j) {
        const int row = j * 32 + sr;
        const int col = sc ^ ((row & 7) * 8);
        GLOAD_LDS16(qkv + base + (size_t)(kn + row) * 3072 + 1024 + h * 64 + col,
                    &Ksm[nxt][j * 2048 + t * 8]);
      }
#pragma unroll
      for (int i = 0; i < 8; ++i)
        v8[i] = *reinterpret_cast<const unsigned int*>(
            qkv + base + (size_t)(kn + vk0 + i) * 3072 + 2048 + h * 64 + vd0);
    }

    // -- S = Q K^T
    f32x4 s[2][4];
#pragma unroll
    for (int mf = 0; mf < 2; ++mf)
#pragma unroll
      for (int nf = 0; nf < 4; ++nf) s[mf][nf] = {0.f, 0.f, 0.f, 0.f};
#pragma unroll
    for (int ks = 0; ks < 2; ++ks) {
      bf16x8 kf[4];
#pragma unroll
      for (int nf = 0; nf < 4; ++nf) {
        const int row = nf * 16 + lc;
        kf[nf] = *reinterpret_cast<const bf16x8*>(
            &Ksm[cur][row * 64 + ((ks * 32 + 8 * lg) ^ ((row & 7) * 8))]);
      }
#pragma unroll
      for (int mf = 0; mf < 2; ++mf)
#pragma unroll
        for (int nf = 0; nf < 4; ++nf)
          s[mf][nf] = mfma16(qf[mf][ks], kf[nf], s[mf][nf]);
    }

    // -- causal mask (diagonal tiles only; wave-uniform branch)
    if (kv0t + 63 > qb0 + w * 32) {
#pragma unroll
      for (int mf = 0; mf < 2; ++mf)
#pragma unroll
        for (int nf = 0; nf < 4; ++nf) {
          const int kg = kv0t + nf * 16 + lc;
#pragma unroll
          for (int r = 0; r < 4; ++r) {
            const int qg = qb0 + w * 32 + mf * 16 + lg * 4 + r;
            if (kg > qg) s[mf][nf][r] = -1e30f;
          }
        }
    }

    // -- defer-max check (lane-local, no shuffles on common path)
    float lm[2][4];
    bool ok = true;
#pragma unroll
    for (int mf = 0; mf < 2; ++mf)
#pragma unroll
      for (int r = 0; r < 4; ++r) {
        lm[mf][r] = fmaxf(fmaxf(s[mf][0][r], s[mf][1][r]),
                          fmaxf(s[mf][2][r], s[mf][3][r]));
        ok = ok && (lm[mf][r] <= mrow[mf][r] + THR);
      }
    if (!__all(ok)) {
#pragma unroll
      for (int mf = 0; mf < 2; ++mf)
#pragma unroll
        for (int r = 0; r < 4; ++r) {
          float pm = lm[mf][r];
#pragma unroll
          for (int off = 8; off >= 1; off >>= 1)
            pm = fmaxf(pm, __shfl_xor(pm, off, 64));
          const float mnew = fmaxf(mrow[mf][r], pm);
          const float a = EXP2F((mrow[mf][r] - mnew) * KS);
          mrow[mf][r] = mnew;
          mK[mf][r] = mnew * KS;
          lsum[mf][r] *= a;
#pragma unroll
          for (int nd = 0; nd < 4; ++nd) oacc[mf][nd][r] *= a;
        }
    }

    // -- P = exp2(s*KS - m*KS), store to wave-private LDS, partial row sums
#pragma unroll
    for (int mf = 0; mf < 2; ++mf)
#pragma unroll
      for (int r = 0; r < 4; ++r) {
        const int pr = mf * 16 + lg * 4 + r;
        float acc = 0.f;
#pragma unroll
        for (int nf = 0; nf < 4; ++nf) {
          const float p = EXP2F(__builtin_fmaf(s[mf][nf][r], KS, -mK[mf][r]));
          acc += p;
          Pw[pr * 64 + ((nf * 16 + lc) ^ ((pr & 7) * 8))] = (bf16)p;
        }
        lsum[mf][r] += acc;
      }

    // -- write prefetched V into Vtm[nxt] (hidden latency; before PV)
    if (hasnext) {
      bf16x8 wlo, whi;
#pragma unroll
      for (int i = 0; i < 8; ++i) {
        wlo[i] = __builtin_bit_cast(bf16, (unsigned short)(v8[i] & 0xffffu));
        whi[i] = __builtin_bit_cast(bf16, (unsigned short)(v8[i] >> 16));
      }
      *reinterpret_cast<bf16x8*>(
          &Vtm[nxt][vd0 * 64 + (vk0 ^ ((vd0 & 7) * 8))]) = wlo;
      *reinterpret_cast<bf16x8*>(
          &Vtm[nxt][(vd0 + 1) * 64 + (vk0 ^ (((vd0 + 1) & 7) * 8))]) = whi;
    }

    // -- O += P @ V
#pragma unroll
    for (int ks = 0; ks < 2; ++ks) {
      bf16x8 pf[2], vf[4];
#pragma unroll
      for (int mf = 0; mf < 2; ++mf) {
        const int row = mf * 16 + lc;
        pf[mf] = *reinterpret_cast<const bf16x8*>(
            &Pw[row * 64 + ((ks * 32 + 8 * lg) ^ ((row & 7) * 8))]);
      }
#pragma unroll
      for (int nd = 0; nd < 4; ++nd) {
        const int row = nd * 16 + lc;
        vf[nd] = *reinterpret_cast<const bf16x8*>(
            &Vtm[cur][row * 64 + ((ks * 32 + 8 * lg) ^ ((row & 7) * 8))]);
      }
#pragma unroll
      for (int mf = 0; mf < 2; ++mf)
#pragma unroll
        for (int nd = 0; nd < 4; ++nd)
          oacc[mf][nd] = mfma16(pf[mf], vf[nd], oacc[mf][nd]);
    }
    __syncthreads();  // drains K gload_lds (vmcnt0) + makes Vtm[nxt] visible
  }

  // -- epilogue: reduce partial row sums once, normalize, store
#pragma unroll
  for (int mf = 0; mf < 2; ++mf)
#pragma unroll
    for (int r = 0; r < 4; ++r) {
      float ls = lsum[mf][r];
#pragma unroll
      for (int off = 8; off >= 1; off >>= 1) ls += __shfl_xor(ls, off, 64);
      lsum[mf][r] = 1.0f / ls;
    }
  const size_t ybase = (size_t)b * 1024 * 1024;
#pragma unroll
  for (int mf = 0; mf < 2; ++mf)
#pragma unroll
    for (int nd = 0; nd < 4; ++nd)
#pragma unroll
      for (int r = 0; r < 4; ++r) {
        const int qg = qb0 + w * 32 + mf * 16 + lg * 4 + r;
        const int d = nd * 16 + lc;
        y[ybase + (size_t)qg * 1024 + h * 64 + d] =
            (bf16)(oacc[mf][nd][r] * lsum[mf][r]);
      }
}

// ---------------------------------------------------------------------------
// Workspace layout (bytes). Total 109,051,904 (~104 MiB).
//   WqkvT 0..6291456 | WoT ..8388608 | WfcT ..16777216 | WpT ..25165824
//   h1/h2 ..41943040 | qkv ..92274688 | y ..109051904 | fc aliases qkv+y
//   x1 lives in d_out (fp32 [8192,1024]).
// ---------------------------------------------------------------------------
extern "C" void kernel_launch(void* const* d_in, const int* in_sizes, int n_in,
                              void* d_out, int out_size, void* d_ws,
                              size_t ws_size, hipStream_t stream) {
  (void)in_sizes; (void)n_in; (void)out_size; (void)ws_size;
  const float* x    = (const float*)d_in[0];
  const float* Wqkv = (const float*)d_in[1];
  const float* bqkv = (const float*)d_in[2];
  const float* Wo   = (const float*)d_in[3];
  const float* bo   = (const float*)d_in[4];
  const float* ln1w = (const float*)d_in[5];
  const float* ln1b = (const float*)d_in[6];
  const float* ln2w = (const float*)d_in[7];
  const float* ln2b = (const float*)d_in[8];
  const float* Wfc  = (const float*)d_in[9];
  const float* bfc  = (const float*)d_in[10];
  const float* Wp   = (const float*)d_in[11];
  const float* bp   = (const float*)d_in[12];
  float* out = (float*)d_out;
  char* ws = (char*)d_ws;

  bf16* WqkvT = (bf16*)(ws + 0);
  bf16* WoT   = (bf16*)(ws + 6291456);
  bf16* WfcT  = (bf16*)(ws + 8388608);
  bf16* WpT   = (bf16*)(ws + 16777216);
  bf16* h1    = (bf16*)(ws + 25165824);  // also h2
  bf16* qkv   = (bf16*)(ws + 41943040);
  bf16* yb    = (bf16*)(ws + 92274688);
  bf16* fc    = (bf16*)(ws + 41943040);  // aliases qkv+y (both dead by then)
  float* x1   = out;                      // residual buffer in d_out

  // weights: cast + transpose to [N,K] bf16
  transpose_cast_kernel<<<dim3(48, 16), 256, 0, stream>>>(Wqkv, WqkvT, 1024, 3072);
  transpose_cast_kernel<<<dim3(16, 16), 256, 0, stream>>>(Wo, WoT, 1024, 1024);
  transpose_cast_kernel<<<dim3(64, 16), 256, 0, stream>>>(Wfc, WfcT, 1024, 4096);
  transpose_cast_kernel<<<dim3(16, 64), 256, 0, stream>>>(Wp, WpT, 4096, 1024);

  // h = LN1(x)
  ln_kernel<<<8192, 256, 0, stream>>>(x, ln1w, ln1b, h1);
  // qkv = h @ Wqkv + bqkv
  gemm_kernel<0><<<dim3(24, 64), 256, 0, stream>>>(h1, WqkvT, bqkv, nullptr,
                                                   nullptr, qkv, 3072, 1024);
  // y = attention(qkv)
  attn_kernel<<<dim3(8, 16, 8), 256, 0, stream>>>(qkv, yb);
  // x1 = x + y @ Wo + bo
  gemm_kernel<2><<<dim3(8, 64), 256, 0, stream>>>(yb, WoT, bo, x, x1, nullptr,
                                                  1024, 1024);
  // h2 = LN2(x1)
  ln_kernel<<<8192, 256, 0, stream>>>(x1, ln2w, ln2b, h1);
  // fc = gelu(h2 @ Wfc + bfc)
  gemm_kernel<1><<<dim3(32, 64), 256, 0, stream>>>(h1, WfcT, bfc, nullptr,
                                                   nullptr, fc, 4096, 1024);
  // out = x1 + fc @ Wp + bp
  gemm_kernel<2><<<dim3(8, 64), 256, 0, stream>>>(fc, WpT, bp, x1, out, nullptr,
                                                  1024, 4096);
}

// Round 4
// 497.209 us; speedup vs baseline: 1.3158x; 1.0574x over previous
//
#include <hip/hip_runtime.h>

// ---------------------------------------------------------------------------
// Transformer block fwd on MI355X (gfx950), bf16 MFMA pipeline.
// B=8 T=1024 C=1024 H=16 D=64, M = B*T = 8192.
// R4 = R3 with the proj2 launch-arg compile fix.
// GEMMs: 256xBN 8-wave phase-split schedule (T2+T3+T4+T5): counted vmcnt
// (never 0 in loop), one raw s_barrier per phase, dbuf LDS, setprio MFMA.
// ---------------------------------------------------------------------------

typedef __bf16 bf16;
typedef bf16 bf16x8 __attribute__((ext_vector_type(8)));
typedef bf16 bf16x4 __attribute__((ext_vector_type(4)));
typedef float f32x4 __attribute__((ext_vector_type(4)));

#define GLOAD_LDS16(g, l)                                                      \
  __builtin_amdgcn_global_load_lds(                                            \
      (const __attribute__((address_space(1))) void*)(g),                      \
      (__attribute__((address_space(3))) void*)(l), 16, 0, 0)

#define S_VMCNT(n) asm volatile("s_waitcnt vmcnt(" #n ")" ::: "memory")
#define S_BAR() __builtin_amdgcn_s_barrier()

#if __has_builtin(__builtin_amdgcn_exp2f)
#define EXP2F(x) __builtin_amdgcn_exp2f(x)
#else
#define EXP2F(x) exp2f(x)
#endif

static __device__ __forceinline__ float fast_rcp(float x) {
#if __has_builtin(__builtin_amdgcn_rcpf)
  return __builtin_amdgcn_rcpf(x);
#else
  return 1.0f / x;
#endif
}

static __device__ __forceinline__ f32x4 mfma16(bf16x8 a, bf16x8 b, f32x4 c) {
  return __builtin_amdgcn_mfma_f32_16x16x32_bf16(a, b, c, 0, 0, 0);
}

// ---------------- LayerNorm: fp32 [8192,1024] -> bf16 [8192,1024] ----------
__global__ __launch_bounds__(256) void ln_kernel(const float* __restrict__ x,
                                                 const float* __restrict__ w,
                                                 const float* __restrict__ b,
                                                 bf16* __restrict__ out) {
  const int row = blockIdx.x;
  const int t = threadIdx.x;
  const float4 v = reinterpret_cast<const float4*>(x + (size_t)row * 1024)[t];
  float s = v.x + v.y + v.z + v.w;
  float s2 = v.x * v.x + v.y * v.y + v.z * v.z + v.w * v.w;
#pragma unroll
  for (int off = 32; off >= 1; off >>= 1) {
    s += __shfl_xor(s, off, 64);
    s2 += __shfl_xor(s2, off, 64);
  }
  __shared__ float red[8];
  if ((t & 63) == 0) {
    red[t >> 6] = s;
    red[4 + (t >> 6)] = s2;
  }
  __syncthreads();
  s = red[0] + red[1] + red[2] + red[3];
  s2 = red[4] + red[5] + red[6] + red[7];
  const float mean = s * (1.0f / 1024.0f);
  const float var = s2 * (1.0f / 1024.0f) - mean * mean;
  const float rstd = rsqrtf(var + 1e-5f);
  const float4 wv = reinterpret_cast<const float4*>(w)[t];
  const float4 bv = reinterpret_cast<const float4*>(b)[t];
  bf16x4 o;
  o[0] = (bf16)((v.x - mean) * rstd * wv.x + bv.x);
  o[1] = (bf16)((v.y - mean) * rstd * wv.y + bv.y);
  o[2] = (bf16)((v.z - mean) * rstd * wv.z + bv.z);
  o[3] = (bf16)((v.w - mean) * rstd * wv.w + bv.w);
  *reinterpret_cast<bf16x4*>(out + (size_t)row * 1024 + t * 4) = o;
}

// ---------------- Weight transpose + cast: W fp32 [K,N] -> Wt bf16 [N,K] ----
__global__ __launch_bounds__(256) void transpose_cast_kernel(
    const float* __restrict__ W, bf16* __restrict__ Wt, int K, int N) {
  __shared__ float tile[64][65];
  const int c0 = blockIdx.x * 64;  // N dim
  const int r0 = blockIdx.y * 64;  // K dim
  const int t = threadIdx.x;
  const int tr = t >> 4;           // 0..15
  const int tc = (t & 15) * 4;     // 0..60
#pragma unroll
  for (int rr = 0; rr < 4; ++rr) {
    const int lr = rr * 16 + tr;
    const float4 v =
        *reinterpret_cast<const float4*>(&W[(size_t)(r0 + lr) * N + c0 + tc]);
    tile[lr][tc] = v.x;
    tile[lr][tc + 1] = v.y;
    tile[lr][tc + 2] = v.z;
    tile[lr][tc + 3] = v.w;
  }
  __syncthreads();
#pragma unroll
  for (int rr = 0; rr < 4; ++rr) {
    const int ln = rr * 16 + tr;
    bf16x4 o;
#pragma unroll
    for (int i = 0; i < 4; ++i) o[i] = (bf16)tile[tc + i][ln];
    *reinterpret_cast<bf16x4*>(&Wt[(size_t)(c0 + ln) * K + r0 + tc]) = o;
  }
}

// ---------------- GEMM 256xBN phase-split: C = A[M,K] * Bt[N,K]^T ----------
// 512 threads = 8 waves (2 M-halves x 4 N-quarters). BK=64, dbuf LDS.
// Per K-tile: 4 phases = C-quadrants (0,0),(0,1),(1,1),(1,0); each phase
// stages one half-tile of tile kt+1 (order A0,B0,B1,A1), waits a COUNTED
// vmcnt (= loads(p-1)+loads(p)), one s_barrier, then MFMAs under setprio(1).
// EPI: 0 = bias->bf16; 1 = bias+gelu->bf16; 2 = bias+resid->f32.
template <int BN, int EPI>
__global__ __launch_bounds__(512, 2) void gemm256_kernel(
    const bf16* __restrict__ A, const bf16* __restrict__ Bt,
    const float* __restrict__ bias, const float* __restrict__ resid,
    float* __restrict__ outf, bf16* __restrict__ outb, int Ndim, int Kdim) {
  constexpr int NB = BN / 128;  // B n-frags per wave per quadrant (1 or 2)
  constexpr int LB = BN / 128;  // gload_lds per thread per B half-tile
  __shared__ __align__(16) bf16 As[2][256 * 64];
  __shared__ __align__(16) bf16 Bs[2][BN * 64];

  const int t = threadIdx.x;
  const int l = t & 63;
  const int w = t >> 6;
  const int lg = l >> 4, lc = l & 15;
  const int wr = w >> 2;  // 0..1 (M half within quadrant rows)
  const int wc = w & 3;   // 0..3 (N quarter within quadrant cols)

  // XCD swizzle: contiguous chunk of tiles per XCD
  const int gx = gridDim.x;
  const int nwg = gx * gridDim.y;
  int flat = blockIdx.x + blockIdx.y * gx;
  if ((nwg & 7) == 0) {
    const int ch = nwg >> 3;
    flat = (flat & 7) * ch + (flat >> 3);
  }
  const int m0 = (flat / gx) * 256;
  const int n0 = (flat % gx) * BN;

  const int sr = t >> 3;       // 0..63 staging row within 64-row group
  const int sc = (t & 7) * 8;  // staging col chunk
  const int scsw = sc ^ ((sr & 7) * 8);  // pre-swizzled source col

  f32x4 acc[2][2][4][NB];
#pragma unroll
  for (int mh = 0; mh < 2; ++mh)
#pragma unroll
    for (int nh = 0; nh < 2; ++nh)
#pragma unroll
      for (int m = 0; m < 4; ++m)
#pragma unroll
        for (int n = 0; n < NB; ++n) acc[mh][nh][m][n] = {0.f, 0.f, 0.f, 0.f};

  bf16x8 af[4][2], bfr[NB][2];

  auto stageA = [&](int buf, int half, int kcol) {
#pragma unroll
    for (int j = 0; j < 2; ++j) {
      const int row = m0 + half * 128 + j * 64 + sr;
      GLOAD_LDS16(A + (size_t)row * Kdim + kcol + scsw,
                  &As[buf][half * 8192 + j * 4096 + t * 8]);
    }
  };
  auto stageB = [&](int buf, int half, int kcol) {
#pragma unroll
    for (int j = 0; j < LB; ++j) {
      const int row = n0 + half * (BN / 2) + j * 64 + sr;
      GLOAD_LDS16(Bt + (size_t)row * Kdim + kcol + scsw,
                  &Bs[buf][half * (BN / 2) * 64 + j * 4096 + t * 8]);
    }
  };
  auto readA = [&](int buf, int mh) {
#pragma unroll
    for (int m = 0; m < 4; ++m) {
      const int row = mh * 128 + wr * 64 + m * 16 + lc;
#pragma unroll
      for (int ks = 0; ks < 2; ++ks)
        af[m][ks] = *reinterpret_cast<const bf16x8*>(
            &As[buf][row * 64 + ((ks * 32 + 8 * lg) ^ ((row & 7) * 8))]);
    }
  };
  auto readB = [&](int buf, int nh) {
#pragma unroll
    for (int n = 0; n < NB; ++n) {
      const int row = nh * (BN / 2) + wc * (BN / 8) + n * 16 + lc;
#pragma unroll
      for (int ks = 0; ks < 2; ++ks)
        bfr[n][ks] = *reinterpret_cast<const bf16x8*>(
            &Bs[buf][row * 64 + ((ks * 32 + 8 * lg) ^ ((row & 7) * 8))]);
    }
  };
  auto domfma = [&](int mh, int nh) {
    __builtin_amdgcn_s_setprio(1);
#pragma unroll
    for (int ks = 0; ks < 2; ++ks)
#pragma unroll
      for (int m = 0; m < 4; ++m)
#pragma unroll
        for (int n = 0; n < NB; ++n)
          acc[mh][nh][m][n] = mfma16(af[m][ks], bfr[n][ks], acc[mh][nh][m][n]);
    __builtin_amdgcn_s_setprio(0);
  };

  const int NT = Kdim >> 6;

  // prologue: stage tile 0 into buf 0, full drain once
  stageA(0, 0, 0);
  stageA(0, 1, 0);
  stageB(0, 0, 0);
  stageB(0, 1, 0);
  S_VMCNT(0);
  S_BAR();

  int cur = 0;
  for (int kt = 0; kt < NT; ++kt) {
    const int nxt = cur ^ 1;
    const int kn = (kt + 1 < NT ? kt + 1 : kt) << 6;  // clamp keeps counts uniform
    // phase 0: quadrant (0,0); stage A-half0 of next tile
    readA(cur, 0);
    readB(cur, 0);
    stageA(nxt, 0, kn);
    S_VMCNT(4);
    S_BAR();
    domfma(0, 0);
    // phase 1: quadrant (0,1); stage B-half0
    readB(cur, 1);
    stageB(nxt, 0, kn);
    if constexpr (BN == 256) S_VMCNT(4); else S_VMCNT(3);
    S_BAR();
    domfma(0, 1);
    // phase 2: quadrant (1,1); stage B-half1
    readA(cur, 1);
    stageB(nxt, 1, kn);
    if constexpr (BN == 256) S_VMCNT(4); else S_VMCNT(2);
    S_BAR();
    domfma(1, 1);
    // phase 3: quadrant (1,0); stage A-half1
    readB(cur, 0);
    stageA(nxt, 1, kn);
    if constexpr (BN == 256) S_VMCNT(4); else S_VMCNT(3);
    S_BAR();
    domfma(1, 0);
    cur = nxt;
  }

  // epilogue
#pragma unroll
  for (int mh = 0; mh < 2; ++mh)
#pragma unroll
    for (int nh = 0; nh < 2; ++nh)
#pragma unroll
      for (int n = 0; n < NB; ++n) {
        const int col = n0 + nh * (BN / 2) + wc * (BN / 8) + n * 16 + lc;
        const float bv = bias[col];
#pragma unroll
        for (int m = 0; m < 4; ++m) {
          const int row0 = m0 + mh * 128 + wr * 64 + m * 16 + lg * 4;
#pragma unroll
          for (int r = 0; r < 4; ++r) {
            const size_t idx = (size_t)(row0 + r) * Ndim + col;
            const float v = acc[mh][nh][m][n][r] + bv;
            if (EPI == 0) {
              outb[idx] = (bf16)v;
            } else if (EPI == 1) {
              // gelu(tanh) == v * sigmoid(2*0.79788456*(v+0.044715 v^3))
              const float e2 =
                  EXP2F(-2.3022074f * (v + 0.044715f * v * v * v));
              outb[idx] = (bf16)(v * fast_rcp(1.0f + e2));
            } else {
              outf[idx] = v + resid[idx];
            }
          }
        }
      }
}

// ---------------- Flash attention (causal), Q-tile 128, KV-tile 64 ----------
// Double-buffered K (global_load_lds) and V (reg-staged transpose), one
// barrier per KV tile. P buffer aliases the dead Q staging LDS (per-wave).
__global__ __launch_bounds__(256) void attn_kernel(const bf16* __restrict__ qkv,
                                                   bf16* __restrict__ y) {
  const int flat = blockIdx.x + (blockIdx.y << 3) + (blockIdx.z << 7);
  const int swz = (flat & 7) * 128 + (flat >> 3);
  const int qt = swz & 7;
  const int h = (swz >> 3) & 15;
  const int b = swz >> 7;
  const int qb0 = qt * 128;

  const int t = threadIdx.x;
  const int l = t & 63;
  const int w = t >> 6;
  const int lg = l >> 4, lc = l & 15;

  __shared__ __align__(16) bf16 QPs[128 * 64];
  __shared__ __align__(16) bf16 Ksm[2][64 * 64];
  __shared__ __align__(16) bf16 Vtm[2][64 * 64];

  const size_t base = (size_t)b * 1024 * 3072;
  const int sr = t >> 3;
  const int sc = (t & 7) * 8;
  const int vd0 = (t & 31) * 2;
  const int vk0 = (t >> 5) * 8;

#pragma unroll
  for (int j = 0; j < 4; ++j) {
    const int row = j * 32 + sr;
    const int col = sc ^ ((row & 7) * 8);
    GLOAD_LDS16(qkv + base + (size_t)(qb0 + row) * 3072 + h * 64 + col,
                &QPs[j * 2048 + t * 8]);
  }
#pragma unroll
  for (int j = 0; j < 2; ++j) {
    const int row = j * 32 + sr;
    const int col = sc ^ ((row & 7) * 8);
    GLOAD_LDS16(qkv + base + (size_t)row * 3072 + 1024 + h * 64 + col,
                &Ksm[0][j * 2048 + t * 8]);
  }
  unsigned int v8[8];
#pragma unroll
  for (int i = 0; i < 8; ++i)
    v8[i] = *reinterpret_cast<const unsigned int*>(
        qkv + base + (size_t)(vk0 + i) * 3072 + 2048 + h * 64 + vd0);
  __syncthreads();

  bf16x8 qf[2][2];
#pragma unroll
  for (int mf = 0; mf < 2; ++mf)
#pragma unroll
    for (int ks = 0; ks < 2; ++ks) {
      const int row = w * 32 + mf * 16 + lc;
      qf[mf][ks] = *reinterpret_cast<const bf16x8*>(
          &QPs[row * 64 + ((ks * 32 + 8 * lg) ^ ((row & 7) * 8))]);
    }
  {
    bf16x8 wlo, whi;
#pragma unroll
    for (int i = 0; i < 8; ++i) {
      wlo[i] = __builtin_bit_cast(bf16, (unsigned short)(v8[i] & 0xffffu));
      whi[i] = __builtin_bit_cast(bf16, (unsigned short)(v8[i] >> 16));
    }
    *reinterpret_cast<bf16x8*>(&Vtm[0][vd0 * 64 + (vk0 ^ ((vd0 & 7) * 8))]) = wlo;
    *reinterpret_cast<bf16x8*>(
        &Vtm[0][(vd0 + 1) * 64 + (vk0 ^ (((vd0 + 1) & 7) * 8))]) = whi;
  }
  __syncthreads();

  bf16* const Pw = &QPs[w * 2048];

  const float KS = 0.04508422f;  // (1/32) * log2(e)
  const float THR = 177.0f;

  float mrow[2][4], mK[2][4], lsum[2][4];
  f32x4 oacc[2][4];
#pragma unroll
  for (int mf = 0; mf < 2; ++mf)
#pragma unroll
    for (int r = 0; r < 4; ++r) {
      mrow[mf][r] = -1e30f;
      mK[mf][r] = 0.f;
      lsum[mf][r] = 0.f;
    }
#pragma unroll
  for (int mf = 0; mf < 2; ++mf)
#pragma unroll
    for (int nd = 0; nd < 4; ++nd) oacc[mf][nd] = {0.f, 0.f, 0.f, 0.f};

  const int nkv = qt * 2 + 2;
  for (int kt = 0; kt < nkv; ++kt) {
    const int cur = kt & 1, nxt = cur ^ 1;
    const int kv0t = kt << 6;
    const bool hasnext = (kt + 1 < nkv);

    if (hasnext) {
      const int kn = (kt + 1) << 6;
#pragma unroll
      for (int j = 0; j < 2; ++j) {
        const int row = j * 32 + sr;
        const int col = sc ^ ((row & 7) * 8);
        GLOAD_LDS16(qkv + base + (size_t)(kn + row) * 3072 + 1024 + h * 64 + col,
                    &Ksm[nxt][j * 2048 + t * 8]);
      }
#pragma unroll
      for (int i = 0; i < 8; ++i)
        v8[i] = *reinterpret_cast<const unsigned int*>(
            qkv + base + (size_t)(kn + vk0 + i) * 3072 + 2048 + h * 64 + vd0);
    }

    f32x4 s[2][4];
#pragma unroll
    for (int mf = 0; mf < 2; ++mf)
#pragma unroll
      for (int nf = 0; nf < 4; ++nf) s[mf][nf] = {0.f, 0.f, 0.f, 0.f};
#pragma unroll
    for (int ks = 0; ks < 2; ++ks) {
      bf16x8 kf[4];
#pragma unroll
      for (int nf = 0; nf < 4; ++nf) {
        const int row = nf * 16 + lc;
        kf[nf] = *reinterpret_cast<const bf16x8*>(
            &Ksm[cur][row * 64 + ((ks * 32 + 8 * lg) ^ ((row & 7) * 8))]);
      }
#pragma unroll
      for (int mf = 0; mf < 2; ++mf)
#pragma unroll
        for (int nf = 0; nf < 4; ++nf)
          s[mf][nf] = mfma16(qf[mf][ks], kf[nf], s[mf][nf]);
    }

    if (kv0t + 63 > qb0 + w * 32) {
#pragma unroll
      for (int mf = 0; mf < 2; ++mf)
#pragma unroll
        for (int nf = 0; nf < 4; ++nf) {
          const int kg = kv0t + nf * 16 + lc;
#pragma unroll
          for (int r = 0; r < 4; ++r) {
            const int qg = qb0 + w * 32 + mf * 16 + lg * 4 + r;
            if (kg > qg) s[mf][nf][r] = -1e30f;
          }
        }
    }

    float lm[2][4];
    bool ok = true;
#pragma unroll
    for (int mf = 0; mf < 2; ++mf)
#pragma unroll
      for (int r = 0; r < 4; ++r) {
        lm[mf][r] = fmaxf(fmaxf(s[mf][0][r], s[mf][1][r]),
                          fmaxf(s[mf][2][r], s[mf][3][r]));
        ok = ok && (lm[mf][r] <= mrow[mf][r] + THR);
      }
    if (!__all(ok)) {
#pragma unroll
      for (int mf = 0; mf < 2; ++mf)
#pragma unroll
        for (int r = 0; r < 4; ++r) {
          float pm = lm[mf][r];
#pragma unroll
          for (int off = 8; off >= 1; off >>= 1)
            pm = fmaxf(pm, __shfl_xor(pm, off, 64));
          const float mnew = fmaxf(mrow[mf][r], pm);
          const float a = EXP2F((mrow[mf][r] - mnew) * KS);
          mrow[mf][r] = mnew;
          mK[mf][r] = mnew * KS;
          lsum[mf][r] *= a;
#pragma unroll
          for (int nd = 0; nd < 4; ++nd) oacc[mf][nd][r] *= a;
        }
    }

#pragma unroll
    for (int mf = 0; mf < 2; ++mf)
#pragma unroll
      for (int r = 0; r < 4; ++r) {
        const int pr = mf * 16 + lg * 4 + r;
        float accp = 0.f;
#pragma unroll
        for (int nf = 0; nf < 4; ++nf) {
          const float p = EXP2F(__builtin_fmaf(s[mf][nf][r], KS, -mK[mf][r]));
          accp += p;
          Pw[pr * 64 + ((nf * 16 + lc) ^ ((pr & 7) * 8))] = (bf16)p;
        }
        lsum[mf][r] += accp;
      }

    if (hasnext) {
      bf16x8 wlo, whi;
#pragma unroll
      for (int i = 0; i < 8; ++i) {
        wlo[i] = __builtin_bit_cast(bf16, (unsigned short)(v8[i] & 0xffffu));
        whi[i] = __builtin_bit_cast(bf16, (unsigned short)(v8[i] >> 16));
      }
      *reinterpret_cast<bf16x8*>(
          &Vtm[nxt][vd0 * 64 + (vk0 ^ ((vd0 & 7) * 8))]) = wlo;
      *reinterpret_cast<bf16x8*>(
          &Vtm[nxt][(vd0 + 1) * 64 + (vk0 ^ (((vd0 + 1) & 7) * 8))]) = whi;
    }

#pragma unroll
    for (int ks = 0; ks < 2; ++ks) {
      bf16x8 pf[2], vf[4];
#pragma unroll
      for (int mf = 0; mf < 2; ++mf) {
        const int row = mf * 16 + lc;
        pf[mf] = *reinterpret_cast<const bf16x8*>(
            &Pw[row * 64 + ((ks * 32 + 8 * lg) ^ ((row & 7) * 8))]);
      }
#pragma unroll
      for (int nd = 0; nd < 4; ++nd) {
        const int row = nd * 16 + lc;
        vf[nd] = *reinterpret_cast<const bf16x8*>(
            &Vtm[cur][row * 64 + ((ks * 32 + 8 * lg) ^ ((row & 7) * 8))]);
      }
#pragma unroll
      for (int mf = 0; mf < 2; ++mf)
#pragma unroll
        for (int nd = 0; nd < 4; ++nd)
          oacc[mf][nd] = mfma16(pf[mf], vf[nd], oacc[mf][nd]);
    }
    __syncthreads();
  }

#pragma unroll
  for (int mf = 0; mf < 2; ++mf)
#pragma unroll
    for (int r = 0; r < 4; ++r) {
      float ls = lsum[mf][r];
#pragma unroll
      for (int off = 8; off >= 1; off >>= 1) ls += __shfl_xor(ls, off, 64);
      lsum[mf][r] = 1.0f / ls;
    }
  const size_t ybase = (size_t)b * 1024 * 1024;
#pragma unroll
  for (int mf = 0; mf < 2; ++mf)
#pragma unroll
    for (int nd = 0; nd < 4; ++nd)
#pragma unroll
      for (int r = 0; r < 4; ++r) {
        const int qg = qb0 + w * 32 + mf * 16 + lg * 4 + r;
        const int d = nd * 16 + lc;
        y[ybase + (size_t)qg * 1024 + h * 64 + d] =
            (bf16)(oacc[mf][nd][r] * lsum[mf][r]);
      }
}

// ---------------------------------------------------------------------------
// Workspace layout (bytes). Total 109,051,904 (~104 MiB).
// ---------------------------------------------------------------------------
extern "C" void kernel_launch(void* const* d_in, const int* in_sizes, int n_in,
                              void* d_out, int out_size, void* d_ws,
                              size_t ws_size, hipStream_t stream) {
  (void)in_sizes; (void)n_in; (void)out_size; (void)ws_size;
  const float* x    = (const float*)d_in[0];
  const float* Wqkv = (const float*)d_in[1];
  const float* bqkv = (const float*)d_in[2];
  const float* Wo   = (const float*)d_in[3];
  const float* bo   = (const float*)d_in[4];
  const float* ln1w = (const float*)d_in[5];
  const float* ln1b = (const float*)d_in[6];
  const float* ln2w = (const float*)d_in[7];
  const float* ln2b = (const float*)d_in[8];
  const float* Wfc  = (const float*)d_in[9];
  const float* bfc  = (const float*)d_in[10];
  const float* Wp   = (const float*)d_in[11];
  const float* bp   = (const float*)d_in[12];
  float* out = (float*)d_out;
  char* ws = (char*)d_ws;

  bf16* WqkvT = (bf16*)(ws + 0);
  bf16* WoT   = (bf16*)(ws + 6291456);
  bf16* WfcT  = (bf16*)(ws + 8388608);
  bf16* WpT   = (bf16*)(ws + 16777216);
  bf16* h1    = (bf16*)(ws + 25165824);  // also h2
  bf16* qkv   = (bf16*)(ws + 41943040);
  bf16* yb    = (bf16*)(ws + 92274688);
  bf16* fc    = (bf16*)(ws + 41943040);  // aliases qkv+y (both dead by then)
  float* x1   = out;

  transpose_cast_kernel<<<dim3(48, 16), 256, 0, stream>>>(Wqkv, WqkvT, 1024, 3072);
  transpose_cast_kernel<<<dim3(16, 16), 256, 0, stream>>>(Wo, WoT, 1024, 1024);
  transpose_cast_kernel<<<dim3(64, 16), 256, 0, stream>>>(Wfc, WfcT, 1024, 4096);
  transpose_cast_kernel<<<dim3(16, 64), 256, 0, stream>>>(Wp, WpT, 4096, 1024);

  ln_kernel<<<8192, 256, 0, stream>>>(x, ln1w, ln1b, h1);
  // qkv = h @ Wqkv + bqkv   [M=8192, N=3072, K=1024]
  gemm256_kernel<256, 0><<<dim3(12, 32), 512, 0, stream>>>(
      h1, WqkvT, bqkv, nullptr, nullptr, qkv, 3072, 1024);
  attn_kernel<<<dim3(8, 16, 8), 256, 0, stream>>>(qkv, yb);
  // x1 = x + y @ Wo + bo    [8192, 1024, 1024] -> 256 blocks exact fill
  gemm256_kernel<128, 2><<<dim3(8, 32), 512, 0, stream>>>(
      yb, WoT, bo, x, x1, nullptr, 1024, 1024);
  ln_kernel<<<8192, 256, 0, stream>>>(x1, ln2w, ln2b, h1);
  // fc = gelu(h2 @ Wfc + bfc)  [8192, 4096, 1024]
  gemm256_kernel<256, 1><<<dim3(16, 32), 512, 0, stream>>>(
      h1, WfcT, bfc, nullptr, nullptr, fc, 4096, 1024);
  // out = x1 + fc @ Wp + bp    [8192, 1024, 4096] -> 256 blocks exact fill
  gemm256_kernel<128, 2><<<dim3(8, 32), 512, 0, stream>>>(
      fc, WpT, bp, x1, out, nullptr, 1024, 4096);
}

// Round 5
// 478.231 us; speedup vs baseline: 1.3680x; 1.0397x over previous
//
#include <hip/hip_runtime.h>

// ---------------------------------------------------------------------------
// Transformer block fwd on MI355X (gfx950), bf16 MFMA pipeline.
// B=8 T=1024 C=1024 H=16 D=64, M = B*T = 8192.
// R5: GEMM phase-split schedule tightened toward the m201 template:
//   - 2 K-tiles per loop iter, literal LDS buffer indices (no runtime cur)
//   - relaxed counted vmcnt: 3 stages in flight (6 / 5,5,4,4 loads)
//   - separate b0/b1 register banks -> phase 3 has no ds_reads
// ---------------------------------------------------------------------------

typedef __bf16 bf16;
typedef bf16 bf16x8 __attribute__((ext_vector_type(8)));
typedef bf16 bf16x4 __attribute__((ext_vector_type(4)));
typedef float f32x4 __attribute__((ext_vector_type(4)));

#define GLOAD_LDS16(g, l)                                                      \
  __builtin_amdgcn_global_load_lds(                                            \
      (const __attribute__((address_space(1))) void*)(g),                      \
      (__attribute__((address_space(3))) void*)(l), 16, 0, 0)

#define S_VMCNT(n) asm volatile("s_waitcnt vmcnt(" #n ")" ::: "memory")
#define S_BAR() __builtin_amdgcn_s_barrier()

#if __has_builtin(__builtin_amdgcn_exp2f)
#define EXP2F(x) __builtin_amdgcn_exp2f(x)
#else
#define EXP2F(x) exp2f(x)
#endif

static __device__ __forceinline__ float fast_rcp(float x) {
#if __has_builtin(__builtin_amdgcn_rcpf)
  return __builtin_amdgcn_rcpf(x);
#else
  return 1.0f / x;
#endif
}

static __device__ __forceinline__ f32x4 mfma16(bf16x8 a, bf16x8 b, f32x4 c) {
  return __builtin_amdgcn_mfma_f32_16x16x32_bf16(a, b, c, 0, 0, 0);
}

// ---------------- LayerNorm: fp32 [8192,1024] -> bf16 [8192,1024] ----------
__global__ __launch_bounds__(256) void ln_kernel(const float* __restrict__ x,
                                                 const float* __restrict__ w,
                                                 const float* __restrict__ b,
                                                 bf16* __restrict__ out) {
  const int row = blockIdx.x;
  const int t = threadIdx.x;
  const float4 v = reinterpret_cast<const float4*>(x + (size_t)row * 1024)[t];
  float s = v.x + v.y + v.z + v.w;
  float s2 = v.x * v.x + v.y * v.y + v.z * v.z + v.w * v.w;
#pragma unroll
  for (int off = 32; off >= 1; off >>= 1) {
    s += __shfl_xor(s, off, 64);
    s2 += __shfl_xor(s2, off, 64);
  }
  __shared__ float red[8];
  if ((t & 63) == 0) {
    red[t >> 6] = s;
    red[4 + (t >> 6)] = s2;
  }
  __syncthreads();
  s = red[0] + red[1] + red[2] + red[3];
  s2 = red[4] + red[5] + red[6] + red[7];
  const float mean = s * (1.0f / 1024.0f);
  const float var = s2 * (1.0f / 1024.0f) - mean * mean;
  const float rstd = rsqrtf(var + 1e-5f);
  const float4 wv = reinterpret_cast<const float4*>(w)[t];
  const float4 bv = reinterpret_cast<const float4*>(b)[t];
  bf16x4 o;
  o[0] = (bf16)((v.x - mean) * rstd * wv.x + bv.x);
  o[1] = (bf16)((v.y - mean) * rstd * wv.y + bv.y);
  o[2] = (bf16)((v.z - mean) * rstd * wv.z + bv.z);
  o[3] = (bf16)((v.w - mean) * rstd * wv.w + bv.w);
  *reinterpret_cast<bf16x4*>(out + (size_t)row * 1024 + t * 4) = o;
}

// ---------------- Weight transpose + cast: W fp32 [K,N] -> Wt bf16 [N,K] ----
__global__ __launch_bounds__(256) void transpose_cast_kernel(
    const float* __restrict__ W, bf16* __restrict__ Wt, int K, int N) {
  __shared__ float tile[64][65];
  const int c0 = blockIdx.x * 64;  // N dim
  const int r0 = blockIdx.y * 64;  // K dim
  const int t = threadIdx.x;
  const int tr = t >> 4;           // 0..15
  const int tc = (t & 15) * 4;     // 0..60
#pragma unroll
  for (int rr = 0; rr < 4; ++rr) {
    const int lr = rr * 16 + tr;
    const float4 v =
        *reinterpret_cast<const float4*>(&W[(size_t)(r0 + lr) * N + c0 + tc]);
    tile[lr][tc] = v.x;
    tile[lr][tc + 1] = v.y;
    tile[lr][tc + 2] = v.z;
    tile[lr][tc + 3] = v.w;
  }
  __syncthreads();
#pragma unroll
  for (int rr = 0; rr < 4; ++rr) {
    const int ln = rr * 16 + tr;
    bf16x4 o;
#pragma unroll
    for (int i = 0; i < 4; ++i) o[i] = (bf16)tile[tc + i][ln];
    *reinterpret_cast<bf16x4*>(&Wt[(size_t)(c0 + ln) * K + r0 + tc]) = o;
  }
}

// ---------------- GEMM 256xBN phase-split: C = A[M,K] * Bt[N,K]^T ----------
// 512 threads = 8 waves (2 M-halves x 4 N-quarters). BK=64, dbuf LDS.
// 2 K-tiles per loop iter (literal buffer indices). Per K-tile 4 phases,
// quadrants (0,0),(0,1),(1,1),(1,0); stage order A0,B0,B1,A1; every read is
// >=3 stages after its stage, so vmcnt allows the 3 newest stages:
// BN=256 -> vmcnt(6) everywhere; BN=128 -> 5,5,4,4 pattern.
// EPI: 0 = bias->bf16; 1 = bias+gelu->bf16; 2 = bias+resid->f32.
template <int BN, int EPI>
__global__ __launch_bounds__(512, 2) void gemm256_kernel(
    const bf16* __restrict__ A, const bf16* __restrict__ Bt,
    const float* __restrict__ bias, const float* __restrict__ resid,
    float* __restrict__ outf, bf16* __restrict__ outb, int Ndim, int Kdim) {
  constexpr int NB = BN / 128;      // B n-frags per wave per quadrant
  constexpr int LB = BN / 128;      // gload_lds per thread per B half stage
  __shared__ __align__(16) bf16 As[2][256 * 64];
  __shared__ __align__(16) bf16 Bs[2][BN * 64];

  const int t = threadIdx.x;
  const int l = t & 63;
  const int w = t >> 6;
  const int lg = l >> 4, lc = l & 15;
  const int wr = w >> 2;  // 0..1 (M half within wave grid)
  const int wc = w & 3;   // 0..3 (N quarter)

  // XCD swizzle: contiguous chunk of tiles per XCD
  const int gx = gridDim.x;
  const int nwg = gx * gridDim.y;
  int flat = blockIdx.x + blockIdx.y * gx;
  if ((nwg & 7) == 0) {
    const int ch = nwg >> 3;
    flat = (flat & 7) * ch + (flat >> 3);
  }
  const int m0 = (flat / gx) * 256;
  const int n0 = (flat % gx) * BN;

  const int sr = t >> 3;                 // staging row 0..63
  const int sc = (t & 7) * 8;            // staging col chunk
  const int scsw = sc ^ ((sr & 7) * 8);  // pre-swizzled source col

  // hoisted staging base pointers (per-thread constant)
  const bf16* const Ap = A + (size_t)(m0 + sr) * Kdim + scsw;
  const bf16* const Bp = Bt + (size_t)(n0 + sr) * Kdim + scsw;

  f32x4 acc[2][2][4][NB];
#pragma unroll
  for (int mh = 0; mh < 2; ++mh)
#pragma unroll
    for (int nh = 0; nh < 2; ++nh)
#pragma unroll
      for (int m = 0; m < 4; ++m)
#pragma unroll
        for (int n = 0; n < NB; ++n) acc[mh][nh][m][n] = {0.f, 0.f, 0.f, 0.f};

  bf16x8 af[4][2], b0[NB][2], b1[NB][2];

  auto stageA = [&](bf16* dst, int half, int kcol) {
#pragma unroll
    for (int j = 0; j < 2; ++j)
      GLOAD_LDS16(Ap + (size_t)(half * 128 + j * 64) * Kdim + kcol,
                  dst + half * 8192 + j * 4096 + t * 8);
  };
  auto stageB = [&](bf16* dst, int half, int kcol) {
#pragma unroll
    for (int j = 0; j < LB; ++j)
      GLOAD_LDS16(Bp + (size_t)(half * (BN / 2) + j * 64) * Kdim + kcol,
                  dst + half * (BN / 2) * 64 + j * 4096 + t * 8);
  };
  auto readA = [&](const bf16* buf, int mh) {
#pragma unroll
    for (int m = 0; m < 4; ++m) {
      const int row = mh * 128 + wr * 64 + m * 16 + lc;
#pragma unroll
      for (int ks = 0; ks < 2; ++ks)
        af[m][ks] = *reinterpret_cast<const bf16x8*>(
            &buf[row * 64 + ((ks * 32 + 8 * lg) ^ ((row & 7) * 8))]);
    }
  };
  auto readB = [&](const bf16* buf, int nh, bf16x8 (&bf)[NB][2]) {
#pragma unroll
    for (int n = 0; n < NB; ++n) {
      const int row = nh * (BN / 2) + wc * (BN / 8) + n * 16 + lc;
#pragma unroll
      for (int ks = 0; ks < 2; ++ks)
        bf[n][ks] = *reinterpret_cast<const bf16x8*>(
            &buf[row * 64 + ((ks * 32 + 8 * lg) ^ ((row & 7) * 8))]);
    }
  };
  auto domfma = [&](int mh, int nh, bf16x8 (&bf)[NB][2]) {
    __builtin_amdgcn_s_setprio(1);
#pragma unroll
    for (int ks = 0; ks < 2; ++ks)
#pragma unroll
      for (int m = 0; m < 4; ++m)
#pragma unroll
        for (int n = 0; n < NB; ++n)
          acc[mh][nh][m][n] = mfma16(af[m][ks], bf[n][ks], acc[mh][nh][m][n]);
    __builtin_amdgcn_s_setprio(0);
  };

  const int NT = Kdim >> 6;
  const int NI = NT >> 1;

  // prologue: stage tile 0 into buf0 (order A0,B0,B1,A1) — no drain needed;
  // the loop's first vmcnt covers exactly the reads of phase 0.
  stageA((bf16*)As[0], 0, 0);
  stageB((bf16*)Bs[0], 0, 0);
  stageB((bf16*)Bs[0], 1, 0);
  stageA((bf16*)As[0], 1, 0);

  for (int it = 0; it < NI; ++it) {
    const int ka = (2 * it + 1) << 6;                            // tile 2it+1
    const int kb = ((2 * it + 2 < NT) ? (2 * it + 2) : (NT - 1)) << 6;

    // ---- K-tile 2it from buf0; stage tile 2it+1 -> buf1 ----
    readA(As[0], 0);
    readB(As[0] ? Bs[0] : Bs[0], 0, b0);  // (plain Bs[0]; keep reads simple)
    stageA((bf16*)As[1], 0, ka);
    if constexpr (BN == 256) S_VMCNT(6); else S_VMCNT(5);
    S_BAR();
    domfma(0, 0, b0);

    readB(Bs[0], 1, b1);
    stageB((bf16*)Bs[1], 0, ka);
    if constexpr (BN == 256) S_VMCNT(6); else S_VMCNT(5);
    S_BAR();
    domfma(0, 1, b1);

    readA(As[0], 1);
    stageB((bf16*)Bs[1], 1, ka);
    if constexpr (BN == 256) S_VMCNT(6); else S_VMCNT(4);
    S_BAR();
    domfma(1, 1, b1);

    stageA((bf16*)As[1], 1, ka);
    if constexpr (BN == 256) S_VMCNT(6); else S_VMCNT(4);
    S_BAR();
    domfma(1, 0, b0);

    // ---- K-tile 2it+1 from buf1; stage tile 2it+2 -> buf0 ----
    readA(As[1], 0);
    readB(Bs[1], 0, b0);
    stageA((bf16*)As[0], 0, kb);
    if constexpr (BN == 256) S_VMCNT(6); else S_VMCNT(5);
    S_BAR();
    domfma(0, 0, b0);

    readB(Bs[1], 1, b1);
    stageB((bf16*)Bs[0], 0, kb);
    if constexpr (BN == 256) S_VMCNT(6); else S_VMCNT(5);
    S_BAR();
    domfma(0, 1, b1);

    readA(As[1], 1);
    stageB((bf16*)Bs[0], 1, kb);
    if constexpr (BN == 256) S_VMCNT(6); else S_VMCNT(4);
    S_BAR();
    domfma(1, 1, b1);

    stageA((bf16*)As[0], 1, kb);
    if constexpr (BN == 256) S_VMCNT(6); else S_VMCNT(4);
    S_BAR();
    domfma(1, 0, b0);
  }

  // epilogue
#pragma unroll
  for (int mh = 0; mh < 2; ++mh)
#pragma unroll
    for (int nh = 0; nh < 2; ++nh)
#pragma unroll
      for (int n = 0; n < NB; ++n) {
        const int col = n0 + nh * (BN / 2) + wc * (BN / 8) + n * 16 + lc;
        const float bv = bias[col];
#pragma unroll
        for (int m = 0; m < 4; ++m) {
          const int row0 = m0 + mh * 128 + wr * 64 + m * 16 + lg * 4;
#pragma unroll
          for (int r = 0; r < 4; ++r) {
            const size_t idx = (size_t)(row0 + r) * Ndim + col;
            const float v = acc[mh][nh][m][n][r] + bv;
            if (EPI == 0) {
              outb[idx] = (bf16)v;
            } else if (EPI == 1) {
              // gelu(tanh) == v * sigmoid(2*0.79788456*(v+0.044715 v^3))
              const float e2 =
                  EXP2F(-2.3022074f * (v + 0.044715f * v * v * v));
              outb[idx] = (bf16)(v * fast_rcp(1.0f + e2));
            } else {
              outf[idx] = v + resid[idx];
            }
          }
        }
      }
}

// ---------------- Flash attention (causal), Q-tile 128, KV-tile 64 ----------
// Double-buffered K (global_load_lds) and V (reg-staged transpose), one
// barrier per KV tile. P buffer aliases the dead Q staging LDS (per-wave).
__global__ __launch_bounds__(256) void attn_kernel(const bf16* __restrict__ qkv,
                                                   bf16* __restrict__ y) {
  const int flat = blockIdx.x + (blockIdx.y << 3) + (blockIdx.z << 7);
  const int swz = (flat & 7) * 128 + (flat >> 3);
  const int qt = swz & 7;
  const int h = (swz >> 3) & 15;
  const int b = swz >> 7;
  const int qb0 = qt * 128;

  const int t = threadIdx.x;
  const int l = t & 63;
  const int w = t >> 6;
  const int lg = l >> 4, lc = l & 15;

  __shared__ __align__(16) bf16 QPs[128 * 64];
  __shared__ __align__(16) bf16 Ksm[2][64 * 64];
  __shared__ __align__(16) bf16 Vtm[2][64 * 64];

  const size_t base = (size_t)b * 1024 * 3072;
  const int sr = t >> 3;
  const int sc = (t & 7) * 8;
  const int vd0 = (t & 31) * 2;
  const int vk0 = (t >> 5) * 8;

#pragma unroll
  for (int j = 0; j < 4; ++j) {
    const int row = j * 32 + sr;
    const int col = sc ^ ((row & 7) * 8);
    GLOAD_LDS16(qkv + base + (size_t)(qb0 + row) * 3072 + h * 64 + col,
                &QPs[j * 2048 + t * 8]);
  }
#pragma unroll
  for (int j = 0; j < 2; ++j) {
    const int row = j * 32 + sr;
    const int col = sc ^ ((row & 7) * 8);
    GLOAD_LDS16(qkv + base + (size_t)row * 3072 + 1024 + h * 64 + col,
                &Ksm[0][j * 2048 + t * 8]);
  }
  unsigned int v8[8];
#pragma unroll
  for (int i = 0; i < 8; ++i)
    v8[i] = *reinterpret_cast<const unsigned int*>(
        qkv + base + (size_t)(vk0 + i) * 3072 + 2048 + h * 64 + vd0);
  __syncthreads();

  bf16x8 qf[2][2];
#pragma unroll
  for (int mf = 0; mf < 2; ++mf)
#pragma unroll
    for (int ks = 0; ks < 2; ++ks) {
      const int row = w * 32 + mf * 16 + lc;
      qf[mf][ks] = *reinterpret_cast<const bf16x8*>(
          &QPs[row * 64 + ((ks * 32 + 8 * lg) ^ ((row & 7) * 8))]);
    }
  {
    bf16x8 wlo, whi;
#pragma unroll
    for (int i = 0; i < 8; ++i) {
      wlo[i] = __builtin_bit_cast(bf16, (unsigned short)(v8[i] & 0xffffu));
      whi[i] = __builtin_bit_cast(bf16, (unsigned short)(v8[i] >> 16));
    }
    *reinterpret_cast<bf16x8*>(&Vtm[0][vd0 * 64 + (vk0 ^ ((vd0 & 7) * 8))]) = wlo;
    *reinterpret_cast<bf16x8*>(
        &Vtm[0][(vd0 + 1) * 64 + (vk0 ^ (((vd0 + 1) & 7) * 8))]) = whi;
  }
  __syncthreads();

  bf16* const Pw = &QPs[w * 2048];

  const float KS = 0.04508422f;  // (1/32) * log2(e)
  const float THR = 177.0f;

  float mrow[2][4], mK[2][4], lsum[2][4];
  f32x4 oacc[2][4];
#pragma unroll
  for (int mf = 0; mf < 2; ++mf)
#pragma unroll
    for (int r = 0; r < 4; ++r) {
      mrow[mf][r] = -1e30f;
      mK[mf][r] = 0.f;
      lsum[mf][r] = 0.f;
    }
#pragma unroll
  for (int mf = 0; mf < 2; ++mf)
#pragma unroll
    for (int nd = 0; nd < 4; ++nd) oacc[mf][nd] = {0.f, 0.f, 0.f, 0.f};

  const int nkv = qt * 2 + 2;
  for (int kt = 0; kt < nkv; ++kt) {
    const int cur = kt & 1, nxt = cur ^ 1;
    const int kv0t = kt << 6;
    const bool hasnext = (kt + 1 < nkv);

    if (hasnext) {
      const int kn = (kt + 1) << 6;
#pragma unroll
      for (int j = 0; j < 2; ++j) {
        const int row = j * 32 + sr;
        const int col = sc ^ ((row & 7) * 8);
        GLOAD_LDS16(qkv + base + (size_t)(kn + row) * 3072 + 1024 + h * 64 + col,
                    &Ksm[nxt][j * 2048 + t * 8]);
      }
#pragma unroll
      for (int i = 0; i < 8; ++i)
        v8[i] = *reinterpret_cast<const unsigned int*>(
            qkv + base + (size_t)(kn + vk0 + i) * 3072 + 2048 + h * 64 + vd0);
    }

    f32x4 s[2][4];
#pragma unroll
    for (int mf = 0; mf < 2; ++mf)
#pragma unroll
      for (int nf = 0; nf < 4; ++nf) s[mf][nf] = {0.f, 0.f, 0.f, 0.f};
#pragma unroll
    for (int ks = 0; ks < 2; ++ks) {
      bf16x8 kf[4];
#pragma unroll
      for (int nf = 0; nf < 4; ++nf) {
        const int row = nf * 16 + lc;
        kf[nf] = *reinterpret_cast<const bf16x8*>(
            &Ksm[cur][row * 64 + ((ks * 32 + 8 * lg) ^ ((row & 7) * 8))]);
      }
#pragma unroll
      for (int mf = 0; mf < 2; ++mf)
#pragma unroll
        for (int nf = 0; nf < 4; ++nf)
          s[mf][nf] = mfma16(qf[mf][ks], kf[nf], s[mf][nf]);
    }

    if (kv0t + 63 > qb0 + w * 32) {
#pragma unroll
      for (int mf = 0; mf < 2; ++mf)
#pragma unroll
        for (int nf = 0; nf < 4; ++nf) {
          const int kg = kv0t + nf * 16 + lc;
#pragma unroll
          for (int r = 0; r < 4; ++r) {
            const int qg = qb0 + w * 32 + mf * 16 + lg * 4 + r;
            if (kg > qg) s[mf][nf][r] = -1e30f;
          }
        }
    }

    float lm[2][4];
    bool ok = true;
#pragma unroll
    for (int mf = 0; mf < 2; ++mf)
#pragma unroll
      for (int r = 0; r < 4; ++r) {
        lm[mf][r] = fmaxf(fmaxf(s[mf][0][r], s[mf][1][r]),
                          fmaxf(s[mf][2][r], s[mf][3][r]));
        ok = ok && (lm[mf][r] <= mrow[mf][r] + THR);
      }
    if (!__all(ok)) {
#pragma unroll
      for (int mf = 0; mf < 2; ++mf)
#pragma unroll
        for (int r = 0; r < 4; ++r) {
          float pm = lm[mf][r];
#pragma unroll
          for (int off = 8; off >= 1; off >>= 1)
            pm = fmaxf(pm, __shfl_xor(pm, off, 64));
          const float mnew = fmaxf(mrow[mf][r], pm);
          const float a = EXP2F((mrow[mf][r] - mnew) * KS);
          mrow[mf][r] = mnew;
          mK[mf][r] = mnew * KS;
          lsum[mf][r] *= a;
#pragma unroll
          for (int nd = 0; nd < 4; ++nd) oacc[mf][nd][r] *= a;
        }
    }

#pragma unroll
    for (int mf = 0; mf < 2; ++mf)
#pragma unroll
      for (int r = 0; r < 4; ++r) {
        const int pr = mf * 16 + lg * 4 + r;
        float accp = 0.f;
#pragma unroll
        for (int nf = 0; nf < 4; ++nf) {
          const float p = EXP2F(__builtin_fmaf(s[mf][nf][r], KS, -mK[mf][r]));
          accp += p;
          Pw[pr * 64 + ((nf * 16 + lc) ^ ((pr & 7) * 8))] = (bf16)p;
        }
        lsum[mf][r] += accp;
      }

    if (hasnext) {
      bf16x8 wlo, whi;
#pragma unroll
      for (int i = 0; i < 8; ++i) {
        wlo[i] = __builtin_bit_cast(bf16, (unsigned short)(v8[i] & 0xffffu));
        whi[i] = __builtin_bit_cast(bf16, (unsigned short)(v8[i] >> 16));
      }
      *reinterpret_cast<bf16x8*>(
          &Vtm[nxt][vd0 * 64 + (vk0 ^ ((vd0 & 7) * 8))]) = wlo;
      *reinterpret_cast<bf16x8*>(
          &Vtm[nxt][(vd0 + 1) * 64 + (vk0 ^ (((vd0 + 1) & 7) * 8))]) = whi;
    }

#pragma unroll
    for (int ks = 0; ks < 2; ++ks) {
      bf16x8 pf[2], vf[4];
#pragma unroll
      for (int mf = 0; mf < 2; ++mf) {
        const int row = mf * 16 + lc;
        pf[mf] = *reinterpret_cast<const bf16x8*>(
            &Pw[row * 64 + ((ks * 32 + 8 * lg) ^ ((row & 7) * 8))]);
      }
#pragma unroll
      for (int nd = 0; nd < 4; ++nd) {
        const int row = nd * 16 + lc;
        vf[nd] = *reinterpret_cast<const bf16x8*>(
            &Vtm[cur][row * 64 + ((ks * 32 + 8 * lg) ^ ((row & 7) * 8))]);
      }
#pragma unroll
      for (int mf = 0; mf < 2; ++mf)
#pragma unroll
        for (int nd = 0; nd < 4; ++nd)
          oacc[mf][nd] = mfma16(pf[mf], vf[nd], oacc[mf][nd]);
    }
    __syncthreads();
  }

#pragma unroll
  for (int mf = 0; mf < 2; ++mf)
#pragma unroll
    for (int r = 0; r < 4; ++r) {
      float ls = lsum[mf][r];
#pragma unroll
      for (int off = 8; off >= 1; off >>= 1) ls += __shfl_xor(ls, off, 64);
      lsum[mf][r] = 1.0f / ls;
    }
  const size_t ybase = (size_t)b * 1024 * 1024;
#pragma unroll
  for (int mf = 0; mf < 2; ++mf)
#pragma unroll
    for (int nd = 0; nd < 4; ++nd)
#pragma unroll
      for (int r = 0; r < 4; ++r) {
        const int qg = qb0 + w * 32 + mf * 16 + lg * 4 + r;
        const int d = nd * 16 + lc;
        y[ybase + (size_t)qg * 1024 + h * 64 + d] =
            (bf16)(oacc[mf][nd][r] * lsum[mf][r]);
      }
}

// ---------------------------------------------------------------------------
// Workspace layout (bytes). Total 109,051,904 (~104 MiB).
// ---------------------------------------------------------------------------
extern "C" void kernel_launch(void* const* d_in, const int* in_sizes, int n_in,
                              void* d_out, int out_size, void* d_ws,
                              size_t ws_size, hipStream_t stream) {
  (void)in_sizes; (void)n_in; (void)out_size; (void)ws_size;
  const float* x    = (const float*)d_in[0];
  const float* Wqkv = (const float*)d_in[1];
  const float* bqkv = (const float*)d_in[2];
  const float* Wo   = (const float*)d_in[3];
  const float* bo   = (const float*)d_in[4];
  const float* ln1w = (const float*)d_in[5];
  const float* ln1b = (const float*)d_in[6];
  const float* ln2w = (const float*)d_in[7];
  const float* ln2b = (const float*)d_in[8];
  const float* Wfc  = (const float*)d_in[9];
  const float* bfc  = (const float*)d_in[10];
  const float* Wp   = (const float*)d_in[11];
  const float* bp   = (const float*)d_in[12];
  float* out = (float*)d_out;
  char* ws = (char*)d_ws;

  bf16* WqkvT = (bf16*)(ws + 0);
  bf16* WoT   = (bf16*)(ws + 6291456);
  bf16* WfcT  = (bf16*)(ws + 8388608);
  bf16* WpT   = (bf16*)(ws + 16777216);
  bf16* h1    = (bf16*)(ws + 25165824);  // also h2
  bf16* qkv   = (bf16*)(ws + 41943040);
  bf16* yb    = (bf16*)(ws + 92274688);
  bf16* fc    = (bf16*)(ws + 41943040);  // aliases qkv+y (both dead by then)
  float* x1   = out;

  transpose_cast_kernel<<<dim3(48, 16), 256, 0, stream>>>(Wqkv, WqkvT, 1024, 3072);
  transpose_cast_kernel<<<dim3(16, 16), 256, 0, stream>>>(Wo, WoT, 1024, 1024);
  transpose_cast_kernel<<<dim3(64, 16), 256, 0, stream>>>(Wfc, WfcT, 1024, 4096);
  transpose_cast_kernel<<<dim3(16, 64), 256, 0, stream>>>(Wp, WpT, 4096, 1024);

  ln_kernel<<<8192, 256, 0, stream>>>(x, ln1w, ln1b, h1);
  // qkv = h @ Wqkv + bqkv   [M=8192, N=3072, K=1024]
  gemm256_kernel<256, 0><<<dim3(12, 32), 512, 0, stream>>>(
      h1, WqkvT, bqkv, nullptr, nullptr, qkv, 3072, 1024);
  attn_kernel<<<dim3(8, 16, 8), 256, 0, stream>>>(qkv, yb);
  // x1 = x + y @ Wo + bo    [8192, 1024, 1024] -> 256 blocks exact fill
  gemm256_kernel<128, 2><<<dim3(8, 32), 512, 0, stream>>>(
      yb, WoT, bo, x, x1, nullptr, 1024, 1024);
  ln_kernel<<<8192, 256, 0, stream>>>(x1, ln2w, ln2b, h1);
  // fc = gelu(h2 @ Wfc + bfc)  [8192, 4096, 1024]
  gemm256_kernel<256, 1><<<dim3(16, 32), 512, 0, stream>>>(
      h1, WfcT, bfc, nullptr, nullptr, fc, 4096, 1024);
  // out = x1 + fc @ Wp + bp    [8192, 1024, 4096] -> 256 blocks exact fill
  gemm256_kernel<128, 2><<<dim3(8, 32), 512, 0, stream>>>(
      fc, WpT, bp, x1, out, nullptr, 1024, 4096);
}